// Round 1
// 206.719 us; speedup vs baseline: 1.0681x; 1.0681x over previous
//
#include <hip/hip_runtime.h>
#include <cstdint>

// LSTM cell with (diagonal) peephole connections, 256^2 8-phase GEMM.
//   K1: cast x|hx -> bf16 A [4096][2048]; cast Wih|Whh -> bf16 W' [4096][2048]
//       with gate-interleaved row permutation np = (h>>4)*64 + g*16 + (h&15)
//       so every 64-wide N group holds all 4 gates for 16 h-values
//       (one wave's 64 N-columns = 4 gate fragments for the same 16 h).
//   K2: 256x256-tile bf16 MFMA GEMM, 512 threads = 8 waves (2M x 4N),
//       wave tile 128M x 64N, acc[8][4], BK=64, double-buffered 128 KiB LDS.
//       8-phase-style schedule: per K-tile 4 phases of
//         {ds_read subtile; stage 2 gload_lds; s_barrier; lgkmcnt(0);
//          setprio(1); 16 MFMA; setprio(0); s_barrier}
//       with COUNTED vmcnt(8) at tile boundaries (next tile's 8 loads stay
//       in flight across the barrier; never vmcnt(0) in the main loop).
//       Staging-into-live-buffer safety: stage of tile t+2 targets buf[t&1];
//       region R may be staged only in a phase AFTER the phase containing the
//       last ds_read of R (trailing barrier follows each wave's lgkmcnt(0),
//       so all reads are COMPLETE before any wave enters the next phase):
//         B region: last read phase 0  -> staged phases 1,2 (2+2 loads)
//         A rows p*64..p*64+63: p0/p2 last read phase 1 -> staged phase 3
//                               p1/p3 last read phase 3 -> staged at block end
//       vmcnt(8) at block end then retires everything except those 8.
//       XOR swizzle (chunk' = chunk ^ (row&7)) applied on the global source
//       side during global_load_lds (dest must stay wave-uniform + lane*16),
//       and on the LDS read side -- same 0-conflict pattern as previous rev.
//       Full LSTM epilogue fused, lane-local: gate g = N-fragment j.

namespace {

constexpr int H   = 1024;   // hidden
constexpr int K2  = 2048;   // I + H
constexpr int BSZ = 4096;   // batch (M)
constexpr size_t OUT_CY = (size_t)BSZ * H;

typedef __attribute__((ext_vector_type(8))) short bf16x8;
typedef __attribute__((ext_vector_type(4))) float f32x4;
typedef __attribute__((ext_vector_type(8))) unsigned short u16x8;

__device__ __forceinline__ unsigned short f2bf(float f) {
  union { float f; uint32_t u; } v; v.f = f;
  uint32_t u = v.u;
  u += 0x7FFFu + ((u >> 16) & 1u);   // round-to-nearest-even
  return (unsigned short)(u >> 16);
}

__device__ __forceinline__ float sigm(float x) {
  return 1.0f / (1.0f + __expf(-x));
}
__device__ __forceinline__ float tanh_fast(float x) {
  return 1.0f - 2.0f / (1.0f + __expf(2.0f * x));
}

__device__ __forceinline__ void gload_lds16(const void* g, void* l) {
  __builtin_amdgcn_global_load_lds(
      (const __attribute__((address_space(1))) void*)g,
      (__attribute__((address_space(3))) void*)l, 16, 0, 0);
}

}  // namespace

// ---- K1: both casts in one launch -------------------------------------------
// blocks [0, 4096): A = bf16([x|hx]); blocks [4096, 8192): W' permuted cast.
// 8 elements / thread (two float4 loads, one 16B store).
__global__ __launch_bounds__(256) void cast_kernel(
    const float* __restrict__ x, const float* __restrict__ hx,
    const float* __restrict__ wih, const float* __restrict__ whh,
    unsigned short* __restrict__ A, unsigned short* __restrict__ W) {
  int b = blockIdx.x;
  bool isW = b >= 4096;
  int t = (isW ? b - 4096 : b) * 256 + threadIdx.x;
  int idx = t * 8;
  int n = idx >> 11;
  int k = idx & 2047;
  const float* s0 = isW ? wih : x;
  const float* s1 = isW ? whh : hx;
  const float* src = (k < H) ? (s0 + (size_t)n * H + k)
                             : (s1 + (size_t)n * H + (k - H));
  float4 v0 = *(const float4*)src;
  float4 v1 = *(const float4*)(src + 4);
  u16x8 o;
  o[0] = f2bf(v0.x); o[1] = f2bf(v0.y); o[2] = f2bf(v0.z); o[3] = f2bf(v0.w);
  o[4] = f2bf(v1.x); o[5] = f2bf(v1.y); o[6] = f2bf(v1.z); o[7] = f2bf(v1.w);
  if (isW) {
    int g = n >> 10, hh = n & 1023;
    int np = ((hh >> 4) << 6) + (g << 4) + (hh & 15);   // 64-wide gate groups
    *(u16x8*)(W + (size_t)np * K2 + k) = o;
  } else {
    *(u16x8*)(A + (size_t)idx) = o;
  }
}

// ---- K2: fused GEMM + LSTM epilogue -----------------------------------------
// grid = (4096/256, 4096/256) = (16, 16), block = 512 (8 waves, 2M x 4N)
__global__ __launch_bounds__(512, 2) void lstm_fused_gemm(
    const unsigned short* __restrict__ A,   // [4096][2048] bf16
    const unsigned short* __restrict__ W,   // [4096][2048] bf16, permuted rows
    const float* __restrict__ cx,
    const float* __restrict__ bias_ih, const float* __restrict__ bias_hh,
    const float* __restrict__ Wpi, const float* __restrict__ Wpf,
    float* __restrict__ out) {
  // [buf][ A 256x64 | B 256x64 ] bf16 = 2 * 32768 shorts = 128 KiB
  __shared__ __align__(16) unsigned short lds[2 * 32768];

  const int tid  = threadIdx.x;
  const int lane = tid & 63;
  const int wave = tid >> 6;
  const int wm   = wave >> 2;          // 0..1: M half
  const int wn   = wave & 3;           // 0..3: N quarter
  const int m0 = blockIdx.x * 256;
  const int w0 = blockIdx.y * 256;     // W' row base

  // staging: thread loads 16B; LDS dest lane-contiguous (global_load_lds rule),
  // XOR swizzle applied to the global source chunk index.
  const int srow   = tid >> 3;                       // 0..63 (row within round)
  const int schunk = ((tid & 7) ^ (srow & 7)) << 3;  // swizzled chunk * 8 hw

  const int col  = lane & 15;
  const int quad = lane >> 4;

  const unsigned short* Asrc = A + (size_t)(m0 + srow) * K2 + schunk;
  const unsigned short* Wsrc = W + (size_t)(w0 + srow) * K2 + schunk;
  const int ldsdst = wave * 512;       // shorts; + buf*32768 (+16384 for B) + p*4096

  f32x4 acc[8][4];
#pragma unroll
  for (int i = 0; i < 8; ++i)
#pragma unroll
    for (int j = 0; j < 4; ++j)
      acc[i][j] = (f32x4){0.f, 0.f, 0.f, 0.f};

  auto stA = [&](int kt, int buf, int p) {
    gload_lds16(Asrc + (size_t)p * 64 * K2 + kt * 64,
                &lds[buf * 32768 + p * 4096 + ldsdst]);
  };
  auto stB = [&](int kt, int buf, int p) {
    gload_lds16(Wsrc + (size_t)p * 64 * K2 + kt * 64,
                &lds[buf * 32768 + 16384 + p * 4096 + ldsdst]);
  };

  // ---- prologue: stage tiles 0 (buf0) and 1 (buf1); wait tile0 only --------
#pragma unroll
  for (int p = 0; p < 4; ++p) stA(0, 0, p);
#pragma unroll
  for (int p = 0; p < 4; ++p) stB(0, 0, p);
#pragma unroll
  for (int p = 0; p < 4; ++p) stA(1, 1, p);
#pragma unroll
  for (int p = 0; p < 4; ++p) stB(1, 1, p);
  asm volatile("s_waitcnt vmcnt(8)" ::: "memory");   // tile0 landed; tile1 in flight
  __builtin_amdgcn_sched_barrier(0);
  __builtin_amdgcn_s_barrier();

  // read-side addressing (shorts): row R at R*64, chunk' = chunk ^ (R&7);
  // R&7 == col&7 for all fragment rows (bases are multiples of 16).
  const int aoff = (wm * 128 + col) * 64;
  const int boff = 16384 + (wn * 64 + col) * 64;
  const int kch0 = ((quad ^ (col & 7)) << 3);        // ks=0: chunk = quad
  const int kch1 = (((4 + quad) ^ (col & 7)) << 3);  // ks=1: chunk = 4+quad

  for (int kt = 0; kt < 32; ++kt) {
    const int buf = kt & 1;
    const unsigned short* Lb = &lds[buf * 32768];
    const bool pf = (kt + 2 < 32);
    bf16x8 bfr[4][2];                                // B frags held across phases
#pragma unroll
    for (int q = 0; q < 4; ++q) {                    // phase: m-frags {2q,2q+1}
      bf16x8 afr[2][2];
      if (q == 0) {
#pragma unroll
        for (int j = 0; j < 4; ++j) {
          bfr[j][0] = *(const bf16x8*)&Lb[boff + j * 1024 + kch0];
          bfr[j][1] = *(const bf16x8*)&Lb[boff + j * 1024 + kch1];
        }
      }
#pragma unroll
      for (int i2 = 0; i2 < 2; ++i2) {
        afr[i2][0] = *(const bf16x8*)&Lb[aoff + (2 * q + i2) * 1024 + kch0];
        afr[i2][1] = *(const bf16x8*)&Lb[aoff + (2 * q + i2) * 1024 + kch1];
      }
      // staged regions' last ds_read is >=1 trailing barrier behind (see header)
      if (q == 1 && pf) { stB(kt + 2, buf, 0); stB(kt + 2, buf, 1); }
      if (q == 2 && pf) { stB(kt + 2, buf, 2); stB(kt + 2, buf, 3); }
      if (q == 3 && pf) { stA(kt + 2, buf, 0); stA(kt + 2, buf, 2); }
      __builtin_amdgcn_s_barrier();
      asm volatile("s_waitcnt lgkmcnt(0)" ::: "memory");
      __builtin_amdgcn_sched_barrier(0);             // rule #18: pin MFMA below wait
      __builtin_amdgcn_s_setprio(1);
#pragma unroll
      for (int i2 = 0; i2 < 2; ++i2)
#pragma unroll
        for (int j = 0; j < 4; ++j) {
          acc[2 * q + i2][j] = __builtin_amdgcn_mfma_f32_16x16x32_bf16(
              afr[i2][0], bfr[j][0], acc[2 * q + i2][j], 0, 0, 0);
          acc[2 * q + i2][j] = __builtin_amdgcn_mfma_f32_16x16x32_bf16(
              afr[i2][1], bfr[j][1], acc[2 * q + i2][j], 0, 0, 0);
        }
      __builtin_amdgcn_s_setprio(0);
      __builtin_amdgcn_s_barrier();
    }
    // block boundary: finish staging tile kt+2, then ensure tile kt+1 landed
    // while kt+2's 8 loads stay in flight (counted vmcnt, never 0 mid-loop).
    if (pf) {
      stA(kt + 2, buf, 1); stA(kt + 2, buf, 3);
      asm volatile("s_waitcnt vmcnt(8)" ::: "memory");
    } else {
      asm volatile("s_waitcnt vmcnt(0)" ::: "memory");  // tail drain
    }
    __builtin_amdgcn_sched_barrier(0);
    __builtin_amdgcn_s_barrier();
  }

  // ---- fused LSTM epilogue ----
  // C/D layout: col = lane&15, row = quad*4 + r.  Gate g = N-fragment j.
  // h = by*64 + wn*16 + col  (inverse of np = (h>>4)*64 + g*16 + (h&15)).
  const int h = blockIdx.y * 64 + wn * 16 + col;
  const float bi  = bias_ih[h]         + bias_hh[h];
  const float bf_ = bias_ih[H + h]     + bias_hh[H + h];
  const float bc  = bias_ih[2 * H + h] + bias_hh[2 * H + h];
  const float bo  = bias_ih[3 * H + h] + bias_hh[3 * H + h];
  const float di = Wpi[(size_t)h * (H + 1)];
  const float df = Wpf[(size_t)h * (H + 1)];
  const int mbase = m0 + wm * 128 + quad * 4;
#pragma unroll
  for (int i = 0; i < 8; ++i) {
#pragma unroll
    for (int r = 0; r < 4; ++r) {
      const int m = mbase + i * 16 + r;
      const float c  = cx[(size_t)m * H + h];
      const float ip = acc[i][0][r] + bi;
      const float fp = acc[i][1][r] + bf_;
      const float cp = acc[i][2][r] + bc;
      const float op = acc[i][3][r] + bo;
      const float ig = sigm(ip + c * di);
      const float fg = sigm(fp + c * df);
      const float cg = tanh_fast(cp);
      const float cy = fg * c + ig * cg;
      const float og = sigm(op + cy * df);   // reference reuses W_peephole_f
      const float hy = og * tanh_fast(cy);
      out[(size_t)m * H + h] = hy;
      out[OUT_CY + (size_t)m * H + h] = cy;
    }
  }
}

extern "C" void kernel_launch(void* const* d_in, const int* in_sizes, int n_in,
                              void* d_out, int out_size, void* d_ws, size_t ws_size,
                              hipStream_t stream) {
  const float* x   = (const float*)d_in[0];
  const float* hx  = (const float*)d_in[1];
  const float* cx  = (const float*)d_in[2];
  const float* wih = (const float*)d_in[3];
  const float* whh = (const float*)d_in[4];
  const float* bih = (const float*)d_in[5];
  const float* bhh = (const float*)d_in[6];
  const float* wpi = (const float*)d_in[7];
  const float* wpf = (const float*)d_in[8];
  // d_in[9] (W_peephole_o) unused: reference reuses W_peephole_f for outgate.
  float* out = (float*)d_out;

  unsigned short* Abf = (unsigned short*)d_ws;
  unsigned short* Wbf = Abf + (size_t)BSZ * K2;

  cast_kernel<<<8192, 256, 0, stream>>>(x, hx, wih, whh, Abf, Wbf);

  dim3 grid(BSZ / 256, (4 * H) / 256);
  lstm_fused_gemm<<<grid, 512, 0, stream>>>(Abf, Wbf, cx, bih, bhh, wpi, wpf, out);
}

// Round 2
// 203.095 us; speedup vs baseline: 1.0872x; 1.0178x over previous
//
#include <hip/hip_runtime.h>
#include <cstdint>

// LSTM cell with (diagonal) peephole connections, 256^2 8-phase GEMM.
//   K1: cast x|hx -> bf16 A [4096][2048]; cast Wih|Whh -> bf16 W' [4096][2048]
//       with gate-interleaved row permutation np = (h>>4)*64 + g*16 + (h&15)
//       so every 64-wide N group holds all 4 gates for 16 h-values.
//   K2: 256x256-tile bf16 MFMA GEMM, 512 threads = 8 waves (2M x 4N),
//       wave tile 128M x 64N, acc[8][4], BK=64, double-buffered 128 KiB LDS.
//       Per K-tile 4 phases of
//         {asm ds_read subtile; stage gload_lds; s_barrier; lgkmcnt(0);
//          sched_barrier; setprio(1); 16 MFMA; setprio(0); s_barrier}
//       with COUNTED vmcnt(8) at tile boundaries only.
//       *** All fragment loads are inline-asm ds_read_b128 (round-2 change):
//       plain C++ reads of lds[] alias the global_load_lds destination, so the
//       compiler inserted its own s_waitcnt vmcnt(0) before every phase's
//       reads, draining the in-flight kt+2 prefetches each phase (~2k cyc/
//       K-tile of exposed L2/L3 latency -> MfmaUtil stuck at 32%). asm reads
//       are invisible to alias analysis; ordering is ours: barriers +
//       lgkmcnt(0) + sched_barrier(0) (rule #18).
//       Staging-into-live-buffer safety (stage of tile t+2 targets buf[t&1],
//       region staged only in a phase after the phase with its last ds_read;
//       each phase's reads complete before its trailing barrier via lgkmcnt):
//         B region p (rows p*64..): read only in phase 0 (by wave wn=p)
//             -> staged phases 1,2
//         A p0 (rows 0-63, wave0 ph0-1), p2 (128-191, wave1 ph0-1)
//             -> staged phase 3
//         A p1 (64-127, wave0 ph2-3), p3 (192-255, wave1 ph2-3)
//             -> staged after phase 3's trailing barrier (block end)
//       vmcnt(8) at block end retires tile kt+1, leaves kt+2's 8 in flight.
//       XCD swizzle: bijective remap so each XCD owns a 4bx x 8by patch
//       (L3-side unique fetch 576KB -> 384KB per XCD per K-step).
//       XOR swizzle (chunk' = chunk ^ (row&7)) on the global source side of
//       global_load_lds and on the LDS read side: 0 bank conflicts (measured).
//       Full LSTM epilogue fused, lane-local: gate g = N-fragment j.

namespace {

constexpr int H   = 1024;   // hidden
constexpr int K2  = 2048;   // I + H
constexpr int BSZ = 4096;   // batch (M)
constexpr size_t OUT_CY = (size_t)BSZ * H;

typedef __attribute__((ext_vector_type(8))) short bf16x8;
typedef __attribute__((ext_vector_type(4))) float f32x4;
typedef __attribute__((ext_vector_type(8))) unsigned short u16x8;

__device__ __forceinline__ unsigned short f2bf(float f) {
  union { float f; uint32_t u; } v; v.f = f;
  uint32_t u = v.u;
  u += 0x7FFFu + ((u >> 16) & 1u);   // round-to-nearest-even
  return (unsigned short)(u >> 16);
}

__device__ __forceinline__ float sigm(float x) {
  return 1.0f / (1.0f + __expf(-x));
}
__device__ __forceinline__ float tanh_fast(float x) {
  return 1.0f - 2.0f / (1.0f + __expf(2.0f * x));
}

__device__ __forceinline__ void gload_lds16(const void* g, void* l) {
  __builtin_amdgcn_global_load_lds(
      (const __attribute__((address_space(1))) void*)g,
      (__attribute__((address_space(3))) void*)l, 16, 0, 0);
}

// raw ds_read_b128 at LDS byte address `addr` -- no memory operand, so the
// compiler cannot tie it to the global_load_lds destinations (no auto-drain).
__device__ __forceinline__ bf16x8 dsr_b128(unsigned addr) {
  bf16x8 r;
  asm volatile("ds_read_b128 %0, %1" : "=v"(r) : "v"(addr));
  return r;
}

}  // namespace

// ---- K1: both casts in one launch -------------------------------------------
// blocks [0, 4096): A = bf16([x|hx]); blocks [4096, 8192): W' permuted cast.
__global__ __launch_bounds__(256) void cast_kernel(
    const float* __restrict__ x, const float* __restrict__ hx,
    const float* __restrict__ wih, const float* __restrict__ whh,
    unsigned short* __restrict__ A, unsigned short* __restrict__ W) {
  int b = blockIdx.x;
  bool isW = b >= 4096;
  int t = (isW ? b - 4096 : b) * 256 + threadIdx.x;
  int idx = t * 8;
  int n = idx >> 11;
  int k = idx & 2047;
  const float* s0 = isW ? wih : x;
  const float* s1 = isW ? whh : hx;
  const float* src = (k < H) ? (s0 + (size_t)n * H + k)
                             : (s1 + (size_t)n * H + (k - H));
  float4 v0 = *(const float4*)src;
  float4 v1 = *(const float4*)(src + 4);
  u16x8 o;
  o[0] = f2bf(v0.x); o[1] = f2bf(v0.y); o[2] = f2bf(v0.z); o[3] = f2bf(v0.w);
  o[4] = f2bf(v1.x); o[5] = f2bf(v1.y); o[6] = f2bf(v1.z); o[7] = f2bf(v1.w);
  if (isW) {
    int g = n >> 10, hh = n & 1023;
    int np = ((hh >> 4) << 6) + (g << 4) + (hh & 15);   // 64-wide gate groups
    *(u16x8*)(W + (size_t)np * K2 + k) = o;
  } else {
    *(u16x8*)(A + (size_t)idx) = o;
  }
}

// ---- K2: fused GEMM + LSTM epilogue -----------------------------------------
// grid = 256 blocks (16x16 logical), block = 512 (8 waves, 2M x 4N)
__global__ __launch_bounds__(512, 2) void lstm_fused_gemm(
    const unsigned short* __restrict__ A,   // [4096][2048] bf16
    const unsigned short* __restrict__ W,   // [4096][2048] bf16, permuted rows
    const float* __restrict__ cx,
    const float* __restrict__ bias_ih, const float* __restrict__ bias_hh,
    const float* __restrict__ Wpi, const float* __restrict__ Wpf,
    float* __restrict__ out) {
  // [buf][ A 256x64 | B 256x64 ] bf16 = 2 * 32768 shorts = 128 KiB
  __shared__ __align__(16) unsigned short lds[2 * 32768];

  const int tid  = threadIdx.x;
  const int lane = tid & 63;
  const int wave = tid >> 6;
  const int wm   = wave >> 2;          // 0..1: M half
  const int wn   = wave & 3;           // 0..3: N quarter

  // XCD-aware bijective remap: linear id b -> XCD b&7 -> 4bx x 8by patch.
  const int b   = blockIdx.y * 16 + blockIdx.x;
  const int xcd = b & 7, idx = b >> 3;
  const int bx  = (xcd & 3) * 4 + (idx & 3);
  const int by  = (xcd >> 2) * 8 + (idx >> 2);
  const int m0 = bx * 256;
  const int w0 = by * 256;             // W' row base

  // staging: thread loads 16B; LDS dest lane-contiguous (global_load_lds rule),
  // XOR swizzle applied to the global source chunk index.
  const int srow   = tid >> 3;                       // 0..63 (row within round)
  const int schunk = ((tid & 7) ^ (srow & 7)) << 3;  // swizzled chunk * 8 hw

  const int col  = lane & 15;
  const int quad = lane >> 4;

  const unsigned short* Asrc = A + (size_t)(m0 + srow) * K2 + schunk;
  const unsigned short* Wsrc = W + (size_t)(w0 + srow) * K2 + schunk;
  const int ldsdst = wave * 512;       // shorts; + buf*32768 (+16384 for B) + p*4096

  f32x4 acc[8][4];
#pragma unroll
  for (int i = 0; i < 8; ++i)
#pragma unroll
    for (int j = 0; j < 4; ++j)
      acc[i][j] = (f32x4){0.f, 0.f, 0.f, 0.f};

  auto stA = [&](int kt, int buf, int p) {
    gload_lds16(Asrc + (size_t)p * 64 * K2 + kt * 64,
                &lds[buf * 32768 + p * 4096 + ldsdst]);
  };
  auto stB = [&](int kt, int buf, int p) {
    gload_lds16(Wsrc + (size_t)p * 64 * K2 + kt * 64,
                &lds[buf * 32768 + 16384 + p * 4096 + ldsdst]);
  };

  // ---- prologue: stage tiles 0 (buf0) and 1 (buf1); wait tile0 only --------
#pragma unroll
  for (int p = 0; p < 4; ++p) stA(0, 0, p);
#pragma unroll
  for (int p = 0; p < 4; ++p) stB(0, 0, p);
#pragma unroll
  for (int p = 0; p < 4; ++p) stA(1, 1, p);
#pragma unroll
  for (int p = 0; p < 4; ++p) stB(1, 1, p);
  asm volatile("s_waitcnt vmcnt(8)" ::: "memory");   // tile0 landed; tile1 in flight
  __builtin_amdgcn_sched_barrier(0);
  __builtin_amdgcn_s_barrier();

  // read-side byte addressing: row R at R*128 B, chunk' = chunk ^ (R&7);
  // R&7 == col&7 for all fragment rows (bases are multiples of 16).
  const unsigned lds0 = (unsigned)(size_t)(__attribute__((address_space(3))) char*)lds;
  const unsigned abase = lds0 + (unsigned)((wm * 128 + col) * 128);
  const unsigned bbase = lds0 + 32768u + (unsigned)((wn * 64 + col) * 128);
  const unsigned kch0 = ((quad ^ (col & 7)) << 4);        // ks=0 byte offset
  const unsigned kch1 = (((4 + quad) ^ (col & 7)) << 4);  // ks=1 byte offset

#pragma unroll 2
  for (int kt = 0; kt < 32; ++kt) {
    const int buf = kt & 1;
    const unsigned boffs = (unsigned)(buf * 65536);
    const bool pf = (kt + 2 < 32);
    bf16x8 bfr[4][2];                                // B frags held across phases
#pragma unroll
    for (int q = 0; q < 4; ++q) {                    // phase: m-frags {2q,2q+1}
      bf16x8 afr[2][2];
      if (q == 0) {
#pragma unroll
        for (int j = 0; j < 4; ++j) {
          bfr[j][0] = dsr_b128(bbase + boffs + j * 2048 + kch0);
          bfr[j][1] = dsr_b128(bbase + boffs + j * 2048 + kch1);
        }
      }
#pragma unroll
      for (int i2 = 0; i2 < 2; ++i2) {
        afr[i2][0] = dsr_b128(abase + boffs + (2 * q + i2) * 2048 + kch0);
        afr[i2][1] = dsr_b128(abase + boffs + (2 * q + i2) * 2048 + kch1);
      }
      // staged regions' last ds_read is >=1 trailing barrier behind (see header)
      if (q == 1 && pf) { stB(kt + 2, buf, 0); stB(kt + 2, buf, 1); }
      if (q == 2 && pf) { stB(kt + 2, buf, 2); stB(kt + 2, buf, 3); }
      if (q == 3 && pf) { stA(kt + 2, buf, 0); stA(kt + 2, buf, 2); }
      __builtin_amdgcn_s_barrier();
      asm volatile("s_waitcnt lgkmcnt(0)" ::: "memory");
      __builtin_amdgcn_sched_barrier(0);             // rule #18: pin MFMA below wait
      __builtin_amdgcn_s_setprio(1);
#pragma unroll
      for (int i2 = 0; i2 < 2; ++i2)                 // k0 batch: 8 independent
#pragma unroll
        for (int j = 0; j < 4; ++j)
          acc[2 * q + i2][j] = __builtin_amdgcn_mfma_f32_16x16x32_bf16(
              afr[i2][0], bfr[j][0], acc[2 * q + i2][j], 0, 0, 0);
#pragma unroll
      for (int i2 = 0; i2 < 2; ++i2)                 // k1 batch
#pragma unroll
        for (int j = 0; j < 4; ++j)
          acc[2 * q + i2][j] = __builtin_amdgcn_mfma_f32_16x16x32_bf16(
              afr[i2][1], bfr[j][1], acc[2 * q + i2][j], 0, 0, 0);
      __builtin_amdgcn_s_setprio(0);
      __builtin_amdgcn_s_barrier();
    }
    // block boundary: finish staging tile kt+2, then ensure tile kt+1 landed
    // while kt+2's 8 loads stay in flight (counted vmcnt, never 0 mid-loop).
    if (pf) {
      stA(kt + 2, buf, 1); stA(kt + 2, buf, 3);
      asm volatile("s_waitcnt vmcnt(8)" ::: "memory");
    } else {
      asm volatile("s_waitcnt vmcnt(0)" ::: "memory");  // tail drain
    }
    __builtin_amdgcn_sched_barrier(0);
    __builtin_amdgcn_s_barrier();
  }

  // ---- fused LSTM epilogue ----
  // C/D layout: col = lane&15, row = quad*4 + r.  Gate g = N-fragment j.
  // h = by*64 + wn*16 + col  (inverse of np = (h>>4)*64 + g*16 + (h&15)).
  const int h = by * 64 + wn * 16 + col;
  const float bi  = bias_ih[h]         + bias_hh[h];
  const float bf_ = bias_ih[H + h]     + bias_hh[H + h];
  const float bc  = bias_ih[2 * H + h] + bias_hh[2 * H + h];
  const float bo  = bias_ih[3 * H + h] + bias_hh[3 * H + h];
  const float di = Wpi[(size_t)h * (H + 1)];
  const float df = Wpf[(size_t)h * (H + 1)];
  const int mbase = m0 + wm * 128 + quad * 4;
#pragma unroll
  for (int i = 0; i < 8; ++i) {
#pragma unroll
    for (int r = 0; r < 4; ++r) {
      const int m = mbase + i * 16 + r;
      const float c  = cx[(size_t)m * H + h];
      const float ip = acc[i][0][r] + bi;
      const float fp = acc[i][1][r] + bf_;
      const float cp = acc[i][2][r] + bc;
      const float op = acc[i][3][r] + bo;
      const float ig = sigm(ip + c * di);
      const float fg = sigm(fp + c * df);
      const float cg = tanh_fast(cp);
      const float cy = fg * c + ig * cg;
      const float og = sigm(op + cy * df);   // reference reuses W_peephole_f
      const float hy = og * tanh_fast(cy);
      out[(size_t)m * H + h] = hy;
      out[OUT_CY + (size_t)m * H + h] = cy;
    }
  }
}

extern "C" void kernel_launch(void* const* d_in, const int* in_sizes, int n_in,
                              void* d_out, int out_size, void* d_ws, size_t ws_size,
                              hipStream_t stream) {
  const float* x   = (const float*)d_in[0];
  const float* hx  = (const float*)d_in[1];
  const float* cx  = (const float*)d_in[2];
  const float* wih = (const float*)d_in[3];
  const float* whh = (const float*)d_in[4];
  const float* bih = (const float*)d_in[5];
  const float* bhh = (const float*)d_in[6];
  const float* wpi = (const float*)d_in[7];
  const float* wpf = (const float*)d_in[8];
  // d_in[9] (W_peephole_o) unused: reference reuses W_peephole_f for outgate.
  float* out = (float*)d_out;

  unsigned short* Abf = (unsigned short*)d_ws;
  unsigned short* Wbf = Abf + (size_t)BSZ * K2;

  cast_kernel<<<8192, 256, 0, stream>>>(x, hx, wih, whh, Abf, Wbf);

  dim3 grid(BSZ / 256, (4 * H) / 256);
  lstm_fused_gemm<<<grid, 512, 0, stream>>>(Abf, Wbf, cx, bih, bhh, wpi, wpf, out);
}